// Round 11
// baseline (174.451 us; speedup 1.0000x reference)
//
#include <hip/hip_runtime.h>
#include <hip/hip_bf16.h>

constexpr int Sq  = 2560;   // sequence length
constexpr int Dm  = 1536;   // model dim
constexpr int NHe = 12;     // heads
constexpr int HDim= 128;    // head dim
constexpr int N3c = 4608;   // 3*Dm
constexpr int TDc = 22;     // temporal freq count
constexpr int SDc = 21;     // spatial freq count
constexpr int HHc = 20;
constexpr int WWc = 32;

typedef __attribute__((ext_vector_type(4)))  float f32x4;
typedef __attribute__((ext_vector_type(16))) float f32x16;
typedef __attribute__((ext_vector_type(8)))  short bf16x8;
typedef __attribute__((ext_vector_type(4)))  unsigned u32x4;

__device__ __forceinline__ short f2bf(float f) {
  __hip_bfloat16 h = __float2bfloat16(f);
  return __builtin_bit_cast(short, h);
}
__device__ __forceinline__ float bf2f(short s) {
  __hip_bfloat16 h = __builtin_bit_cast(__hip_bfloat16, s);
  return __bfloat162float(h);
}
__device__ __forceinline__ void gll16(const void* g, void* l) {
  __builtin_amdgcn_global_load_lds((const __attribute__((address_space(1))) unsigned int*)g,
                                   (__attribute__((address_space(3))) unsigned int*)l, 16, 0, 0);
}
// packed bf16 convert: dst.lo = bf16(lo), dst.hi = bf16(hi)
__device__ __forceinline__ unsigned cvtpk(float lo, float hi) {
  unsigned r;
  asm("v_cvt_pk_bf16_f32 %0, %1, %2" : "=v"(r) : "v"(lo), "v"(hi));
  return r;
}

// ---- fused preamble: x convert + Wqkv transpose-cvt + Wo transpose-cvt ----
// All three are mutually independent; one launch removes 2 serialization
// points (r9 A/B: fusion = -5.5us vs separate launches). Block-range dispatch;
// branch is uniform per block so __syncthreads stays legal.
constexpr int NCONV = Sq * Dm / 4 / 256;            // 3840
constexpr int NW1x  = N3c / 32;                     // 144
constexpr int NW1   = NW1x * (Dm / 32);             // 6912
constexpr int NW2x  = Dm / 32;                      // 48
constexpr int NW2   = NW2x * (Dm / 32);             // 2304
__global__ __launch_bounds__(256) void k_prep(const float* __restrict__ x,
                                              short* __restrict__ xb,
                                              const float* __restrict__ Wq,
                                              short* __restrict__ WqT,
                                              const float* __restrict__ Wo,
                                              short* __restrict__ WoT) {
  int b = blockIdx.x, tid = threadIdx.x;
  if (b < NCONV) {  // elementwise f32 -> bf16
    int i = b * 256 + tid;
    float4 v = reinterpret_cast<const float4*>(x)[i];
    short4 o;
    o.x = f2bf(v.x); o.y = f2bf(v.y); o.z = f2bf(v.z); o.w = f2bf(v.w);
    reinterpret_cast<short4*>(xb)[i] = o;
    return;
  }
  __shared__ float tile[32][33];
  const float* in; short* out; int R, C_, bx, by;
  if (b < NCONV + NW1) {
    int bb = b - NCONV;
    in = Wq; out = WqT; R = Dm; C_ = N3c; bx = bb % NW1x; by = bb / NW1x;
  } else {
    int bb = b - NCONV - NW1;
    in = Wo; out = WoT; R = Dm; C_ = Dm; bx = bb % NW2x; by = bb / NW2x;
  }
  int c0 = bx * 32, r0 = by * 32;
  int tx = tid & 31, ty = tid >> 5;
#pragma unroll
  for (int i = 0; i < 4; ++i)
    tile[ty + i * 8][tx] = in[(size_t)(r0 + ty + i * 8) * C_ + c0 + tx];
  __syncthreads();
#pragma unroll
  for (int i = 0; i < 4; ++i)
    out[(size_t)(c0 + ty + i * 8) * R + r0 + tx] = f2bf(tile[tx][ty + i * 8]);
}

// ---------------- GEMM: C[M][N] = A[M][K] * BT[N][K] + bias, bf16 in, f32 acc -------
// BM x 128 tile; BM=128: 4 waves as 2x2 of 64x64; BM=64: 2x2 of 32x64.
// BK=32*NP via NP [*][32] LDS panels per operand (gll16 needs lane-linear dest).
// NP ladder measured: NP=1->2 = -7.5us (fewer vmcnt(0)+barrier drains); NP=3
// REGRESSED (r8: LDS 48KB -> 3 blocks/CU occupancy cliff). NP=2 = optimum.
// Block->tile mapping MODE:
//   0 = mt-major linear XCD chunk (GEMM2: all-B + few-A per XCD)
//   2 = 2D XCD regions (GEMM1): XCDs on a 2x4 grid, each owns MTRxNTR tiles,
//       mt fast-varying -> per-region-column A working set = MTR panels
//       (10*0.39MB = 3.9MB <= 4MB L2, so A re-reads become L2 hits; r8 FETCH
//       analysis: nt-major chunking re-read all 20 A panels/XCD = 7.9MB > L2).
// LDS-read swizzle considered and REJECTED: m252 regime gate — T2 null on
// 2-barrier GEMM structures (critical path is stage+drain, not LDS read).
// NOTE (r5): tile choice is grid-fill-dependent — BM=128 on GEMM2 gives 240
// blocks < 256 CUs and measured ~9us SLOWER than BM=64's 480. Keep GEMM2 BM=64.
template <int OUT_BF16, int BM, int MODE, int NP, int MTR = 0, int NTR = 0>
__global__ __launch_bounds__(256) void k_gemm_bt(const short* __restrict__ A,
                                                 const short* __restrict__ BT,
                                                 const float* __restrict__ bias,
                                                 void* __restrict__ Cp,
                                                 int M, int N, int K, int den) {
  constexpr int MF = BM / 32;           // m-frags per wave
  __shared__ short As[NP * BM * 32];    // [panel][BM][32]
  __shared__ short Bs[NP * 128 * 32];   // [panel][128][32]
  int mt, nt;
  if (MODE == 2) {
    int xcd = blockIdx.x & 7, loc = blockIdx.x >> 3;   // loc in [0, MTR*NTR)
    int xr = xcd >> 2, xc = xcd & 3;                   // 2x4 XCD grid
    mt = xr * MTR + loc % MTR;
    nt = xc * NTR + loc / MTR;
  } else {
    int cpx = gridDim.x >> 3;           // chunk per XCD (grid divisible by 8)
    int bid = (blockIdx.x & 7) * cpx + (blockIdx.x >> 3);
    mt = bid / den; nt = bid % den;     // den = N/128
  }
  int tid = threadIdx.x, lane = tid & 63, wid = tid >> 6;
  int wr = wid >> 1, wc = wid & 1;
  f32x4 zero = {0.f, 0.f, 0.f, 0.f};
  f32x4 acc[MF][4];
#pragma unroll
  for (int m = 0; m < MF; ++m)
#pragma unroll
    for (int n = 0; n < 4; ++n) acc[m][n] = zero;

  int lrow = lane >> 2;        // 0..15 within a 16-row staging chunk
  int lk8 = (lane & 3) * 8;    // element offset (8 bf16 = 16B)
  const size_t arow0 = (size_t)mt * BM, brow0 = (size_t)nt * 128;
  int la = lane & 15, lg = lane >> 4;

  for (int kk = 0; kk < K; kk += 32 * NP) {
#pragma unroll
    for (int h = 0; h < NP; ++h) {
#pragma unroll
      for (int i = 0; i < MF / 2; ++i) {
        int rA = (wid * (MF / 2) + i) * 16 + lrow;
        gll16(A + (arow0 + rA) * K + kk + h * 32 + lk8,
              As + h * BM * 32 + rA * 32 + lk8);
      }
#pragma unroll
      for (int i = 0; i < 2; ++i) {
        int rB = (wid * 2 + i) * 16 + lrow;
        gll16(BT + (brow0 + rB) * K + kk + h * 32 + lk8,
              Bs + h * 128 * 32 + rB * 32 + lk8);
      }
    }
    __syncthreads();
#pragma unroll
    for (int h = 0; h < NP; ++h) {
      bf16x8 af[MF], bfr[4];
#pragma unroll
      for (int m = 0; m < MF; ++m)
        af[m] = *(const bf16x8*)(As + h * BM * 32 + (wr * (BM / 2) + m * 16 + la) * 32 + lg * 8);
#pragma unroll
      for (int n = 0; n < 4; ++n)
        bfr[n] = *(const bf16x8*)(Bs + h * 128 * 32 + (wc * 64 + n * 16 + la) * 32 + lg * 8);
#pragma unroll
      for (int m = 0; m < MF; ++m)
#pragma unroll
        for (int n = 0; n < 4; ++n)
          acc[m][n] = __builtin_amdgcn_mfma_f32_16x16x32_bf16(af[m], bfr[n], acc[m][n], 0, 0, 0);
    }
    __syncthreads();
  }
#pragma unroll
  for (int m = 0; m < MF; ++m) {
    int r = (int)arow0 + wr * (BM / 2) + m * 16 + lg * 4;
#pragma unroll
    for (int n = 0; n < 4; ++n) {
      int c = (int)brow0 + wc * 64 + n * 16 + la;
      float b = bias[c];
#pragma unroll
      for (int i = 0; i < 4; ++i) {
        float v = acc[m][n][i] + b;
        if (OUT_BF16) ((short*)Cp)[(size_t)(r + i) * N + c] = f2bf(v);
        else          ((float*)Cp)[(size_t)(r + i) * N + c] = v;
      }
    }
  }
}

// ---- fused mid-stage: RMS+RoPE (Q,K) + V^T transpose, both reading qkvb ----
// rmsrope no longer copies V to head-major (the old Vb round-trip: 7.9MB write
// + 7.9MB re-read); the transpose branch reads V columns straight out of qkvb
// (row stride N3c, offset 2*Dm + h*128) and writes VT. Both branches depend
// only on GEMM1 -> legal in one launch (r10 A/B: -4.1us).
constexpr int NVT_PER_H = (HDim / 32) * (Sq / 32);  // 4*80 = 320
constexpr int NVT = NHe * NVT_PER_H;                // 3840
__global__ __launch_bounds__(256) void k_mid(const short* __restrict__ qkv,
                                             const float* __restrict__ freqs,
                                             const float* __restrict__ gq,
                                             const float* __restrict__ gk,
                                             short* __restrict__ Q,
                                             short* __restrict__ Kx,
                                             short* __restrict__ VT) {
  int b = blockIdx.x, tid = threadIdx.x;
  if (b >= Sq) {  // ---- V^T: VT[h][d][t] = qkv[t][2*Dm + h*128 + d] ----
    __shared__ short tile[32][34];
    int b2 = b - Sq;
    int h = b2 / NVT_PER_H, rem = b2 % NVT_PER_H;
    int c0 = (rem % (HDim / 32)) * 32;   // d block
    int r0 = (rem / (HDim / 32)) * 32;   // t block
    const short* ih = qkv + 2 * Dm + h * HDim;
    short* oh = VT + (size_t)h * HDim * Sq;
    int tx = tid & 31, ty = tid >> 5;
#pragma unroll
    for (int i = 0; i < 4; ++i)
      tile[ty + i * 8][tx] = ih[(size_t)(r0 + ty + i * 8) * N3c + c0 + tx];
    __syncthreads();
#pragma unroll
    for (int i = 0; i < 4; ++i)
      oh[(size_t)(c0 + ty + i * 8) * Sq + r0 + tx] = tile[tx][ty + i * 8];
    return;
  }
  // ---- RMS norm + 3D RoPE -> head-major Q,K ----
  int s = b;
  const short* row = qkv + (size_t)s * N3c;
  __shared__ float cs[64], sn[64];
  __shared__ float wred[8];
  __shared__ float inv_s[2];
  if (tid < 64) {
    int f = s / (HHc * WWc), hh = (s / WWc) % HHc, ww = s % WWc;
    int ridx = tid < TDc ? f : (tid < TDc + SDc ? hh : ww);
    float ang = freqs[ridx * 64 + tid];
    cs[tid] = cosf(ang);
    sn[tid] = sinf(ang);
  }
  float sq = 0.f, sk = 0.f;
  if (tid < 192) {  // 192*8 = 1536, vectorized bf16x8 loads
    bf16x8 a = *(const bf16x8*)(row + tid * 8);
    bf16x8 bb = *(const bf16x8*)(row + Dm + tid * 8);
#pragma unroll
    for (int j = 0; j < 8; ++j) {
      float fa = bf2f(a[j]); sq += fa * fa;
      float fb = bf2f(bb[j]); sk += fb * fb;
    }
  }
#pragma unroll
  for (int o = 32; o > 0; o >>= 1) { sq += __shfl_down(sq, o); sk += __shfl_down(sk, o); }
  if ((tid & 63) == 0) { wred[tid >> 6] = sq; wred[4 + (tid >> 6)] = sk; }
  __syncthreads();
  if (tid == 0) {
    float a = wred[0] + wred[1] + wred[2] + wred[3];
    float bb = wred[4] + wred[5] + wred[6] + wred[7];
    inv_s[0] = rsqrtf(a * (1.0f / Dm) + 1e-6f);
    inv_s[1] = rsqrtf(bb * (1.0f / Dm) + 1e-6f);
  }
  __syncthreads();
  float invq = inv_s[0], invk = inv_s[1];
  // 1/sqrt(HD) * log2(e) folded into Q so softmax uses exp2 directly
  const float qscale = 0.12751763f;
  for (int p = tid; p < NHe * 64; p += 256) {
    int hd = p >> 6, i = p & 63;
    float c = cs[i], sn_ = sn[i];
    int col = hd * HDim + 2 * i;
    size_t obase = ((size_t)hd * Sq + s) * HDim + 2 * i;
    float xr = bf2f(row[col])     * invq * gq[col];
    float xi = bf2f(row[col + 1]) * invq * gq[col + 1];
    Q[obase]     = f2bf((xr * c - xi * sn_) * qscale);
    Q[obase + 1] = f2bf((xr * sn_ + xi * c) * qscale);
    float yr = bf2f(row[Dm + col])     * invk * gk[col];
    float yi = bf2f(row[Dm + col + 1]) * invk * gk[col + 1];
    Kx[obase]     = f2bf(yr * c - yi * sn_);
    Kx[obase + 1] = f2bf(yr * sn_ + yi * c);
  }
}

// ---- flash attention: 64 q-rows/block, 4 waves = 2 q-subblocks x 2 K-halves ----
// Exact round-0 proven structure (64.5-65.3us measured across 6 rounds; no
// setprio — A/B r3/r5 showed it null-to-negative on this lockstep schedule).
// Wave (qw,kw): 32 q-rows (qw), K-half kw via its own ping-pong LDS pipeline.
// In-block split-K: partials combined through LDS at epilogue (no HBM round-trip).
// 32x32x16 MFMA, swapped QK^T, in-register P (cvt_pk + permlane32_swap),
// fixed-max softmax (M2=8*log2e; log2e folded into Q scale).
__global__ __launch_bounds__(256, 2) void k_attn(const short* __restrict__ Q,
                                                 const short* __restrict__ Kg,
                                                 const short* __restrict__ VT,
                                                 short* __restrict__ O) {
  __shared__ short Xb[2][64 * 128];  // K tiles [t][d], swizzle (r&15)<<4, per kw
  __shared__ short Yb[2][64 * 128];  // V tiles [d][t] (128x64), swizzle (r&7)<<4
  __shared__ float Lsh[4][32];
  constexpr int NT = (Sq / 2) / 64;  // 20 tiles per K-half
  // chunked XCD remap: consecutive bid (same head) -> same XCD L2
  int bid = (blockIdx.x & 7) * 60 + (blockIdx.x >> 3);
  int h = bid / 40;
  int q0 = (bid % 40) * 64;
  int tid = threadIdx.x, lane = tid & 63, wid = tid >> 6;
  int qw = wid & 1, kw = wid >> 1;
  int la = lane & 31, hi = lane >> 5;
  const short* Qh = Q  + (size_t)h * Sq * HDim;
  const short* Kh = Kg + (size_t)h * Sq * HDim;
  const short* Vh = VT + (size_t)h * HDim * Sq;
  int qb = q0 + qw * 32;
  int tz = kw * (Sq / 2);
  short* X = Xb[kw];
  short* Y = Yb[kw];

  // staging: 2 waves (qw=0,1) per pipeline, 8 chunks each (pre-swizzled source)
  int koff[8], voff[8], ldo[8];
  const short* Kt = Kh + (size_t)tz * HDim;
  const short* Vt = Vh + tz;
#pragma unroll
  for (int i = 0; i < 8; ++i) {
    int off = (qw * 8 + i) * 1024 + lane * 16;   // byte offset in 16KB tile
    int r  = off >> 8, cb  = off & 255;          // K tile: 256B rows
    koff[i] = r * HDim + ((cb ^ ((r & 15) << 4)) >> 1);
    int r2 = off >> 7, cb2 = off & 127;          // V tile: 128B rows
    voff[i] = r2 * Sq + ((cb2 ^ ((r2 & 7) << 4)) >> 1);
    ldo[i] = off >> 1;
  }
  auto stageK = [&]() {
#pragma unroll
    for (int i = 0; i < 8; ++i) gll16(Kt + koff[i], X + ldo[i]);
    Kt += 64 * HDim;
  };
  auto stageV = [&]() {
#pragma unroll
    for (int i = 0; i < 8; ++i) gll16(Vt + voff[i], Y + ldo[i]);
    Vt += 64;
  };

  stageK();  // K(0)

  // Q B-fragments: lane holds Q[q=la][d = dc*16 + hi*8 + j]
  bf16x8 qf[8];
#pragma unroll
  for (int dc = 0; dc < 8; ++dc)
    qf[dc] = *(const bf16x8*)(Qh + (size_t)(qb + la) * HDim + dc * 16 + hi * 8);

  f32x16 o0, o1, o2, o3;
#pragma unroll
  for (int r = 0; r < 16; ++r) { o0[r] = 0.f; o1[r] = 0.f; o2[r] = 0.f; o3[r] = 0.f; }
  float lsum = 0.f;
  const float M2 = 11.5415603f;  // 8 * log2(e)

  __syncthreads();  // vmcnt(0) drain: K(0) ready

  for (int t = 0; t < NT; ++t) {
    stageV();  // V(t), overlaps QK

    // ---- QK^T swapped: s = K(tile) . Q^T  (rows t, cols q) ----
    f32x16 s0, s1;
#pragma unroll
    for (int r = 0; r < 16; ++r) { s0[r] = 0.f; s1[r] = 0.f; }
    int kcb = ((la & 15) << 4);
#pragma unroll
    for (int dc = 0; dc < 8; ++dc) {
      int bc = (dc * 32 + hi * 16) ^ kcb;
      bf16x8 k0 = *(const bf16x8*)(X + la * 128 + (bc >> 1));
      bf16x8 k1 = *(const bf16x8*)(X + (32 + la) * 128 + (bc >> 1));
      s0 = __builtin_amdgcn_mfma_f32_32x32x16_bf16(k0, qf[dc], s0, 0, 0, 0);
      s1 = __builtin_amdgcn_mfma_f32_32x32x16_bf16(k1, qf[dc], s1, 0, 0, 0);
    }

    // ---- softmax (fixed max): p = 2^(s - M2); lane owns q-row la, half 'hi' ----
    float p0[16], p1[16];
#pragma unroll
    for (int r = 0; r < 16; ++r) { p0[r] = exp2f(s0[r] - M2); p1[r] = exp2f(s1[r] - M2); }
    float a0 = 0.f, a1 = 0.f, a2 = 0.f, a3 = 0.f;
#pragma unroll
    for (int m = 0; m < 4; ++m) {
      a0 += p0[m]; a1 += p0[4 + m]; a2 += p0[8 + m]; a3 += p0[12 + m];
      a0 += p1[m]; a1 += p1[4 + m]; a2 += p1[8 + m]; a3 += p1[12 + m];
    }
    lsum += (a0 + a1) + (a2 + a3);

    // pack pairs: w[tb][m] covers t = tb*32 + 8*(m>>1) + 4*hi + 2*(m&1) + {0,1}
    unsigned w0[8], w1[8];
#pragma unroll
    for (int m = 0; m < 8; ++m) {
      w0[m] = cvtpk(p0[2 * m], p0[2 * m + 1]);
      w1[m] = cvtpk(p1[2 * m], p1[2 * m + 1]);
    }
    // permlane32_swap: r0={A.lo,B.lo} -> word jl, r1={A.hi,B.hi} -> word jl+2
    unsigned paw[4][4];
#pragma unroll
    for (int tcl = 0; tcl < 2; ++tcl)
#pragma unroll
      for (int jl = 0; jl < 2; ++jl) {
        unsigned A0 = w0[4 * tcl + jl], B0 = w0[4 * tcl + 2 + jl];
        asm("v_permlane32_swap_b32 %0, %1" : "+v"(A0), "+v"(B0));
        paw[tcl][jl] = A0; paw[tcl][2 + jl] = B0;
        unsigned A1 = w1[4 * tcl + jl], B1 = w1[4 * tcl + 2 + jl];
        asm("v_permlane32_swap_b32 %0, %1" : "+v"(A1), "+v"(B1));
        paw[2 + tcl][jl] = A1; paw[2 + tcl][2 + jl] = B1;
      }
    bf16x8 pa[4];
#pragma unroll
    for (int tc = 0; tc < 4; ++tc) {
      u32x4 tw = {paw[tc][0], paw[tc][1], paw[tc][2], paw[tc][3]};
      pa[tc] = __builtin_bit_cast(bf16x8, tw);
    }

    __syncthreads();  // V(t) staged & X consumed by all waves

    if (t + 1 < NT) stageK();  // K(t+1), overlaps PV

    // ---- PV: o[db] += P . V  (A=pa in regs, B=V^T tile from LDS) ----
    int vcb = ((la & 7) << 4);
#pragma unroll
    for (int tc = 0; tc < 4; ++tc) {
      int bc = (tc * 32 + hi * 16) ^ vcb;
      bf16x8 vf0 = *(const bf16x8*)(Y + (la)      * 64 + (bc >> 1));
      bf16x8 vf1 = *(const bf16x8*)(Y + (32 + la) * 64 + (bc >> 1));
      bf16x8 vf2 = *(const bf16x8*)(Y + (64 + la) * 64 + (bc >> 1));
      bf16x8 vf3 = *(const bf16x8*)(Y + (96 + la) * 64 + (bc >> 1));
      o0 = __builtin_amdgcn_mfma_f32_32x32x16_bf16(pa[tc], vf0, o0, 0, 0, 0);
      o1 = __builtin_amdgcn_mfma_f32_32x32x16_bf16(pa[tc], vf1, o1, 0, 0, 0);
      o2 = __builtin_amdgcn_mfma_f32_32x32x16_bf16(pa[tc], vf2, o2, 0, 0, 0);
      o3 = __builtin_amdgcn_mfma_f32_32x32x16_bf16(pa[tc], vf3, o3, 0, 0, 0);
    }
    __syncthreads();  // K(t+1) staged & Y consumed by all waves
  }

  // ---- in-block split-K combine (through LDS; pipelines are dead now) ----
  {  // full half-row sum: own hi-half + partner hi-half
    float A = lsum, B = lsum;
    asm("v_permlane32_swap_b32 %0, %1" : "+v"(A), "+v"(B));
    lsum = A + B;
  }
  if (hi == 0) Lsh[wid][la] = lsum;
  float* fb = (float*)(&Xb[0][0]);  // 32KB scratch: [qw][64 floats][lane]
  if (kw == 1) {
    float* dst = fb + qw * 4096 + lane;
#pragma unroll
    for (int r = 0; r < 16; ++r) {
      dst[(r)      * 64] = o0[r];
      dst[(16 + r) * 64] = o1[r];
      dst[(32 + r) * 64] = o2[r];
      dst[(48 + r) * 64] = o3[r];
    }
  }
  __syncthreads();
  if (kw == 0) {
    float ltot = lsum + Lsh[wid + 2][la];
    float rinv = 1.0f / ltot;
    if (hi == 0) Lsh[wid][la] = rinv;   // same-wave LDS broadcast
    const float* src = fb + qw * 4096 + lane;
#pragma unroll
    for (int r = 0; r < 16; ++r) {
      o0[r] += src[(r)      * 64];
      o1[r] += src[(16 + r) * 64];
      o2[r] += src[(32 + r) * 64];
      o3[r] += src[(48 + r) * 64];
    }
    float rv[16];
#pragma unroll
    for (int r = 0; r < 16; ++r)
      rv[r] = Lsh[wid][(r & 3) + 8 * (r >> 2) + 4 * hi];
#pragma unroll
    for (int r = 0; r < 16; ++r) {
      int qrow = qb + (r & 3) + 8 * (r >> 2) + 4 * hi;
      short* orow = O + (size_t)qrow * Dm + h * HDim + la;
      orow[0]  = f2bf(o0[r] * rv[r]);
      orow[32] = f2bf(o1[r] * rv[r]);
      orow[64] = f2bf(o2[r] * rv[r]);
      orow[96] = f2bf(o3[r] * rv[r]);
    }
  }
}

extern "C" void kernel_launch(void* const* d_in, const int* in_sizes, int n_in,
                              void* d_out, int out_size, void* d_ws, size_t ws_size,
                              hipStream_t stream) {
  const float* x     = (const float*)d_in[0];
  const float* freqs = (const float*)d_in[3];
  const float* Wqkv  = (const float*)d_in[4];
  const float* bqkv  = (const float*)d_in[5];
  const float* gq    = (const float*)d_in[6];
  const float* gk    = (const float*)d_in[7];
  const float* Wo    = (const float*)d_in[8];
  const float* bo    = (const float*)d_in[9];
  float* out = (float*)d_out;

  char* w = (char*)d_ws;
  // region0: Q,K (head-major) + spare slot — xb and WqT overlaid (dead after GEMM1)
  short* Qb  = (short*)w;
  short* Kb  = Qb + (size_t)Sq * Dm;
  short* xb  = Qb;                      // 2560*1536 bf16, fits in Qb slot
  short* WqT = Kb;                      // 4608*1536 bf16, fits in Kb + spare slots
  size_t off = (size_t)3 * Sq * Dm * 2;
  short* WoT  = (short*)(w + off); off += (size_t)Dm * Dm * 2;
  short* qkvb = (short*)(w + off); off += (size_t)Sq * N3c * 2;
  short* VTb  = (short*)(w + off); off += (size_t)Sq * Dm * 2;
  short* AOb  = (short*)(w + off); off += (size_t)Sq * Dm * 2;

  // 1. fused preamble: x convert + both weight transposes in ONE launch
  k_prep<<<NCONV + NW1 + NW2, 256, 0, stream>>>(x, xb, Wqkv, WqT, Wo, WoT);
  // 2. QKV GEMM -> bf16 (BK=64; MODE=2: 2x4 XCD grid of 10mt x 9nt regions,
  //    mt-fast -> per-column A working set 3.9MB fits 4MB L2)
  k_gemm_bt<1, 128, 2, 2, 10, 9><<<(Sq / 128) * (N3c / 128), 256, 0, stream>>>(
      xb, WqT, bqkv, qkvb, Sq, N3c, Dm, N3c / 128);
  // 3. fused mid-stage: RMS+RoPE (Q,K) + V^T straight from qkvb
  k_mid<<<Sq + NVT, 256, 0, stream>>>(qkvb, freqs, gq, gk, Qb, Kb, VTb);
  // 4. flash attention: 480 blocks (40 q-blocks x 12 heads), in-block split-K
  k_attn<<<480, 256, 0, stream>>>(Qb, Kb, VTb, AOb);
  // 5. output projection -> f32, BM=64 BK=64 MODE=0 (480 blocks ~2/CU; BM=128's
  //    240 blocks underfill 256 CUs — r5: 9us slower). mt-major XCD chunk.
  k_gemm_bt<0, 64, 0, 2><<<(Sq / 64) * (Dm / 128), 256, 0, stream>>>(AOb, WoT, bo, out,
                                                                     Sq, Dm, Dm, Dm / 128);
}

// Round 12
// 159.966 us; speedup vs baseline: 1.0905x; 1.0905x over previous
//
#include <hip/hip_runtime.h>
#include <hip/hip_bf16.h>

constexpr int Sq  = 2560;   // sequence length
constexpr int Dm  = 1536;   // model dim
constexpr int NHe = 12;     // heads
constexpr int HDim= 128;    // head dim
constexpr int N3c = 4608;   // 3*Dm
constexpr int TDc = 22;     // temporal freq count
constexpr int SDc = 21;     // spatial freq count
constexpr int HHc = 20;
constexpr int WWc = 32;

typedef __attribute__((ext_vector_type(4)))  float f32x4;
typedef __attribute__((ext_vector_type(16))) float f32x16;
typedef __attribute__((ext_vector_type(8)))  short bf16x8;
typedef __attribute__((ext_vector_type(4)))  unsigned u32x4;

__device__ __forceinline__ short f2bf(float f) {
  __hip_bfloat16 h = __float2bfloat16(f);
  return __builtin_bit_cast(short, h);
}
__device__ __forceinline__ float bf2f(short s) {
  __hip_bfloat16 h = __builtin_bit_cast(__hip_bfloat16, s);
  return __bfloat162float(h);
}
__device__ __forceinline__ void gll16(const void* g, void* l) {
  __builtin_amdgcn_global_load_lds((const __attribute__((address_space(1))) unsigned int*)g,
                                   (__attribute__((address_space(3))) unsigned int*)l, 16, 0, 0);
}
// packed bf16 convert: dst.lo = bf16(lo), dst.hi = bf16(hi)
__device__ __forceinline__ unsigned cvtpk(float lo, float hi) {
  unsigned r;
  asm("v_cvt_pk_bf16_f32 %0, %1, %2" : "=v"(r) : "v"(lo), "v"(hi));
  return r;
}

// ---- fused preamble: x convert + Wqkv transpose-cvt + Wo transpose-cvt ----
// All three are mutually independent; one launch removes 2 serialization
// points (r9 A/B: fusion = -5.5us vs separate launches). Block-range dispatch;
// branch is uniform per block so __syncthreads stays legal.
constexpr int NCONV = Sq * Dm / 4 / 256;            // 3840
constexpr int NW1x  = N3c / 32;                     // 144
constexpr int NW1   = NW1x * (Dm / 32);             // 6912
constexpr int NW2x  = Dm / 32;                      // 48
constexpr int NW2   = NW2x * (Dm / 32);             // 2304
__global__ __launch_bounds__(256) void k_prep(const float* __restrict__ x,
                                              short* __restrict__ xb,
                                              const float* __restrict__ Wq,
                                              short* __restrict__ WqT,
                                              const float* __restrict__ Wo,
                                              short* __restrict__ WoT) {
  int b = blockIdx.x, tid = threadIdx.x;
  if (b < NCONV) {  // elementwise f32 -> bf16
    int i = b * 256 + tid;
    float4 v = reinterpret_cast<const float4*>(x)[i];
    short4 o;
    o.x = f2bf(v.x); o.y = f2bf(v.y); o.z = f2bf(v.z); o.w = f2bf(v.w);
    reinterpret_cast<short4*>(xb)[i] = o;
    return;
  }
  __shared__ float tile[32][33];
  const float* in; short* out; int R, C_, bx, by;
  if (b < NCONV + NW1) {
    int bb = b - NCONV;
    in = Wq; out = WqT; R = Dm; C_ = N3c; bx = bb % NW1x; by = bb / NW1x;
  } else {
    int bb = b - NCONV - NW1;
    in = Wo; out = WoT; R = Dm; C_ = Dm; bx = bb % NW2x; by = bb / NW2x;
  }
  int c0 = bx * 32, r0 = by * 32;
  int tx = tid & 31, ty = tid >> 5;
#pragma unroll
  for (int i = 0; i < 4; ++i)
    tile[ty + i * 8][tx] = in[(size_t)(r0 + ty + i * 8) * C_ + c0 + tx];
  __syncthreads();
#pragma unroll
  for (int i = 0; i < 4; ++i)
    out[(size_t)(c0 + ty + i * 8) * R + r0 + tx] = f2bf(tile[tx][ty + i * 8]);
}

// ---------------- GEMM: C[M][N] = A[M][K] * BT[N][K] + bias, bf16 in, f32 acc -------
// BM x 128 tile; BM=128: 4 waves as 2x2 of 64x64; BM=64: 2x2 of 32x64.
// BK=32*NP via NP [*][32] LDS panels per operand (gll16 needs lane-linear dest).
// NP ladder measured: NP=1->2 = -7.5us (fewer vmcnt(0)+barrier drains); NP=3
// REGRESSED (r8: LDS 48KB -> 3 blocks/CU occupancy cliff). NP=2 = optimum.
// Mapping ladder measured (GEMM1): nt-major linear XCD chunk = BEST; 2D
// 10x9-per-XCD regions (r11) cut FETCH 70.7->46.1MB but ran 14us SLOWER —
// this structure is latency-bound, and the sequential A-panel stream under a
// shared B-panel beats the traffic-minimal order. Do NOT re-try traffic opts.
// LDS-read swizzle considered and REJECTED: m252 regime gate — T2 null on
// 2-barrier GEMM structures (critical path is stage+drain, not LDS read).
// NOTE (r5): tile choice is grid-fill-dependent — BM=128 on GEMM2 gives 240
// blocks < 256 CUs and measured ~9us SLOWER than BM=64's 480. Keep GEMM2 BM=64.
template <int OUT_BF16, int BM, int NTMAJOR, int NP>
__global__ __launch_bounds__(256) void k_gemm_bt(const short* __restrict__ A,
                                                 const short* __restrict__ BT,
                                                 const float* __restrict__ bias,
                                                 void* __restrict__ Cp,
                                                 int M, int N, int K, int den) {
  constexpr int MF = BM / 32;           // m-frags per wave
  __shared__ short As[NP * BM * 32];    // [panel][BM][32]
  __shared__ short Bs[NP * 128 * 32];   // [panel][128][32]
  int cpx = gridDim.x >> 3;             // chunk per XCD (grid divisible by 8)
  int bid = (blockIdx.x & 7) * cpx + (blockIdx.x >> 3);
  int mt, nt;
  if (NTMAJOR) { mt = bid % den; nt = bid / den; }   // den = M/BM
  else         { mt = bid / den; nt = bid % den; }   // den = N/128
  int tid = threadIdx.x, lane = tid & 63, wid = tid >> 6;
  int wr = wid >> 1, wc = wid & 1;
  f32x4 zero = {0.f, 0.f, 0.f, 0.f};
  f32x4 acc[MF][4];
#pragma unroll
  for (int m = 0; m < MF; ++m)
#pragma unroll
    for (int n = 0; n < 4; ++n) acc[m][n] = zero;

  int lrow = lane >> 2;        // 0..15 within a 16-row staging chunk
  int lk8 = (lane & 3) * 8;    // element offset (8 bf16 = 16B)
  const size_t arow0 = (size_t)mt * BM, brow0 = (size_t)nt * 128;
  int la = lane & 15, lg = lane >> 4;

  for (int kk = 0; kk < K; kk += 32 * NP) {
#pragma unroll
    for (int h = 0; h < NP; ++h) {
#pragma unroll
      for (int i = 0; i < MF / 2; ++i) {
        int rA = (wid * (MF / 2) + i) * 16 + lrow;
        gll16(A + (arow0 + rA) * K + kk + h * 32 + lk8,
              As + h * BM * 32 + rA * 32 + lk8);
      }
#pragma unroll
      for (int i = 0; i < 2; ++i) {
        int rB = (wid * 2 + i) * 16 + lrow;
        gll16(BT + (brow0 + rB) * K + kk + h * 32 + lk8,
              Bs + h * 128 * 32 + rB * 32 + lk8);
      }
    }
    __syncthreads();
#pragma unroll
    for (int h = 0; h < NP; ++h) {
      bf16x8 af[MF], bfr[4];
#pragma unroll
      for (int m = 0; m < MF; ++m)
        af[m] = *(const bf16x8*)(As + h * BM * 32 + (wr * (BM / 2) + m * 16 + la) * 32 + lg * 8);
#pragma unroll
      for (int n = 0; n < 4; ++n)
        bfr[n] = *(const bf16x8*)(Bs + h * 128 * 32 + (wc * 64 + n * 16 + la) * 32 + lg * 8);
#pragma unroll
      for (int m = 0; m < MF; ++m)
#pragma unroll
        for (int n = 0; n < 4; ++n)
          acc[m][n] = __builtin_amdgcn_mfma_f32_16x16x32_bf16(af[m], bfr[n], acc[m][n], 0, 0, 0);
    }
    __syncthreads();
  }
#pragma unroll
  for (int m = 0; m < MF; ++m) {
    int r = (int)arow0 + wr * (BM / 2) + m * 16 + lg * 4;
#pragma unroll
    for (int n = 0; n < 4; ++n) {
      int c = (int)brow0 + wc * 64 + n * 16 + la;
      float b = bias[c];
#pragma unroll
      for (int i = 0; i < 4; ++i) {
        float v = acc[m][n][i] + b;
        if (OUT_BF16) ((short*)Cp)[(size_t)(r + i) * N + c] = f2bf(v);
        else          ((float*)Cp)[(size_t)(r + i) * N + c] = v;
      }
    }
  }
}

// ---- fused mid-stage: RMS+RoPE (Q,K) + V^T transpose, both reading qkvb ----
// rmsrope no longer copies V to head-major (the old Vb round-trip: 7.9MB write
// + 7.9MB re-read); the transpose branch reads V columns straight out of qkvb
// (row stride N3c, offset 2*Dm + h*128) and writes VT. Both branches depend
// only on GEMM1 -> legal in one launch (r10 A/B: -4.1us).
constexpr int NVT_PER_H = (HDim / 32) * (Sq / 32);  // 4*80 = 320
constexpr int NVT = NHe * NVT_PER_H;                // 3840
__global__ __launch_bounds__(256) void k_mid(const short* __restrict__ qkv,
                                             const float* __restrict__ freqs,
                                             const float* __restrict__ gq,
                                             const float* __restrict__ gk,
                                             short* __restrict__ Q,
                                             short* __restrict__ Kx,
                                             short* __restrict__ VT) {
  int b = blockIdx.x, tid = threadIdx.x;
  if (b >= Sq) {  // ---- V^T: VT[h][d][t] = qkv[t][2*Dm + h*128 + d] ----
    __shared__ short tile[32][34];
    int b2 = b - Sq;
    int h = b2 / NVT_PER_H, rem = b2 % NVT_PER_H;
    int c0 = (rem % (HDim / 32)) * 32;   // d block
    int r0 = (rem / (HDim / 32)) * 32;   // t block
    const short* ih = qkv + 2 * Dm + h * HDim;
    short* oh = VT + (size_t)h * HDim * Sq;
    int tx = tid & 31, ty = tid >> 5;
#pragma unroll
    for (int i = 0; i < 4; ++i)
      tile[ty + i * 8][tx] = ih[(size_t)(r0 + ty + i * 8) * N3c + c0 + tx];
    __syncthreads();
#pragma unroll
    for (int i = 0; i < 4; ++i)
      oh[(size_t)(c0 + ty + i * 8) * Sq + r0 + tx] = tile[tx][ty + i * 8];
    return;
  }
  // ---- RMS norm + 3D RoPE -> head-major Q,K ----
  int s = b;
  const short* row = qkv + (size_t)s * N3c;
  __shared__ float cs[64], sn[64];
  __shared__ float wred[8];
  __shared__ float inv_s[2];
  if (tid < 64) {
    int f = s / (HHc * WWc), hh = (s / WWc) % HHc, ww = s % WWc;
    int ridx = tid < TDc ? f : (tid < TDc + SDc ? hh : ww);
    float ang = freqs[ridx * 64 + tid];
    cs[tid] = cosf(ang);
    sn[tid] = sinf(ang);
  }
  float sq = 0.f, sk = 0.f;
  if (tid < 192) {  // 192*8 = 1536, vectorized bf16x8 loads
    bf16x8 a = *(const bf16x8*)(row + tid * 8);
    bf16x8 bb = *(const bf16x8*)(row + Dm + tid * 8);
#pragma unroll
    for (int j = 0; j < 8; ++j) {
      float fa = bf2f(a[j]); sq += fa * fa;
      float fb = bf2f(bb[j]); sk += fb * fb;
    }
  }
#pragma unroll
  for (int o = 32; o > 0; o >>= 1) { sq += __shfl_down(sq, o); sk += __shfl_down(sk, o); }
  if ((tid & 63) == 0) { wred[tid >> 6] = sq; wred[4 + (tid >> 6)] = sk; }
  __syncthreads();
  if (tid == 0) {
    float a = wred[0] + wred[1] + wred[2] + wred[3];
    float bb = wred[4] + wred[5] + wred[6] + wred[7];
    inv_s[0] = rsqrtf(a * (1.0f / Dm) + 1e-6f);
    inv_s[1] = rsqrtf(bb * (1.0f / Dm) + 1e-6f);
  }
  __syncthreads();
  float invq = inv_s[0], invk = inv_s[1];
  // 1/sqrt(HD) * log2(e) folded into Q so softmax uses exp2 directly
  const float qscale = 0.12751763f;
  for (int p = tid; p < NHe * 64; p += 256) {
    int hd = p >> 6, i = p & 63;
    float c = cs[i], sn_ = sn[i];
    int col = hd * HDim + 2 * i;
    size_t obase = ((size_t)hd * Sq + s) * HDim + 2 * i;
    float xr = bf2f(row[col])     * invq * gq[col];
    float xi = bf2f(row[col + 1]) * invq * gq[col + 1];
    Q[obase]     = f2bf((xr * c - xi * sn_) * qscale);
    Q[obase + 1] = f2bf((xr * sn_ + xi * c) * qscale);
    float yr = bf2f(row[Dm + col])     * invk * gk[col];
    float yi = bf2f(row[Dm + col + 1]) * invk * gk[col + 1];
    Kx[obase]     = f2bf(yr * c - yi * sn_);
    Kx[obase + 1] = f2bf(yr * sn_ + yi * c);
  }
}

// ---- flash attention: 64 q-rows/block, 4 waves = 2 q-subblocks x 2 K-halves ----
// Exact round-0 proven structure (64.5-65.3us measured across 7 rounds; no
// setprio — A/B r3/r5 showed it null-to-negative on this lockstep schedule).
// Wave (qw,kw): 32 q-rows (qw), K-half kw via its own ping-pong LDS pipeline.
// In-block split-K: partials combined through LDS at epilogue (no HBM round-trip).
// 32x32x16 MFMA, swapped QK^T, in-register P (cvt_pk + permlane32_swap),
// fixed-max softmax (M2=8*log2e; log2e folded into Q scale).
__global__ __launch_bounds__(256, 2) void k_attn(const short* __restrict__ Q,
                                                 const short* __restrict__ Kg,
                                                 const short* __restrict__ VT,
                                                 short* __restrict__ O) {
  __shared__ short Xb[2][64 * 128];  // K tiles [t][d], swizzle (r&15)<<4, per kw
  __shared__ short Yb[2][64 * 128];  // V tiles [d][t] (128x64), swizzle (r&7)<<4
  __shared__ float Lsh[4][32];
  constexpr int NT = (Sq / 2) / 64;  // 20 tiles per K-half
  // chunked XCD remap: consecutive bid (same head) -> same XCD L2
  int bid = (blockIdx.x & 7) * 60 + (blockIdx.x >> 3);
  int h = bid / 40;
  int q0 = (bid % 40) * 64;
  int tid = threadIdx.x, lane = tid & 63, wid = tid >> 6;
  int qw = wid & 1, kw = wid >> 1;
  int la = lane & 31, hi = lane >> 5;
  const short* Qh = Q  + (size_t)h * Sq * HDim;
  const short* Kh = Kg + (size_t)h * Sq * HDim;
  const short* Vh = VT + (size_t)h * HDim * Sq;
  int qb = q0 + qw * 32;
  int tz = kw * (Sq / 2);
  short* X = Xb[kw];
  short* Y = Yb[kw];

  // staging: 2 waves (qw=0,1) per pipeline, 8 chunks each (pre-swizzled source)
  int koff[8], voff[8], ldo[8];
  const short* Kt = Kh + (size_t)tz * HDim;
  const short* Vt = Vh + tz;
#pragma unroll
  for (int i = 0; i < 8; ++i) {
    int off = (qw * 8 + i) * 1024 + lane * 16;   // byte offset in 16KB tile
    int r  = off >> 8, cb  = off & 255;          // K tile: 256B rows
    koff[i] = r * HDim + ((cb ^ ((r & 15) << 4)) >> 1);
    int r2 = off >> 7, cb2 = off & 127;          // V tile: 128B rows
    voff[i] = r2 * Sq + ((cb2 ^ ((r2 & 7) << 4)) >> 1);
    ldo[i] = off >> 1;
  }
  auto stageK = [&]() {
#pragma unroll
    for (int i = 0; i < 8; ++i) gll16(Kt + koff[i], X + ldo[i]);
    Kt += 64 * HDim;
  };
  auto stageV = [&]() {
#pragma unroll
    for (int i = 0; i < 8; ++i) gll16(Vt + voff[i], Y + ldo[i]);
    Vt += 64;
  };

  stageK();  // K(0)

  // Q B-fragments: lane holds Q[q=la][d = dc*16 + hi*8 + j]
  bf16x8 qf[8];
#pragma unroll
  for (int dc = 0; dc < 8; ++dc)
    qf[dc] = *(const bf16x8*)(Qh + (size_t)(qb + la) * HDim + dc * 16 + hi * 8);

  f32x16 o0, o1, o2, o3;
#pragma unroll
  for (int r = 0; r < 16; ++r) { o0[r] = 0.f; o1[r] = 0.f; o2[r] = 0.f; o3[r] = 0.f; }
  float lsum = 0.f;
  const float M2 = 11.5415603f;  // 8 * log2(e)

  __syncthreads();  // vmcnt(0) drain: K(0) ready

  for (int t = 0; t < NT; ++t) {
    stageV();  // V(t), overlaps QK

    // ---- QK^T swapped: s = K(tile) . Q^T  (rows t, cols q) ----
    f32x16 s0, s1;
#pragma unroll
    for (int r = 0; r < 16; ++r) { s0[r] = 0.f; s1[r] = 0.f; }
    int kcb = ((la & 15) << 4);
#pragma unroll
    for (int dc = 0; dc < 8; ++dc) {
      int bc = (dc * 32 + hi * 16) ^ kcb;
      bf16x8 k0 = *(const bf16x8*)(X + la * 128 + (bc >> 1));
      bf16x8 k1 = *(const bf16x8*)(X + (32 + la) * 128 + (bc >> 1));
      s0 = __builtin_amdgcn_mfma_f32_32x32x16_bf16(k0, qf[dc], s0, 0, 0, 0);
      s1 = __builtin_amdgcn_mfma_f32_32x32x16_bf16(k1, qf[dc], s1, 0, 0, 0);
    }

    // ---- softmax (fixed max): p = 2^(s - M2); lane owns q-row la, half 'hi' ----
    float p0[16], p1[16];
#pragma unroll
    for (int r = 0; r < 16; ++r) { p0[r] = exp2f(s0[r] - M2); p1[r] = exp2f(s1[r] - M2); }
    float a0 = 0.f, a1 = 0.f, a2 = 0.f, a3 = 0.f;
#pragma unroll
    for (int m = 0; m < 4; ++m) {
      a0 += p0[m]; a1 += p0[4 + m]; a2 += p0[8 + m]; a3 += p0[12 + m];
      a0 += p1[m]; a1 += p1[4 + m]; a2 += p1[8 + m]; a3 += p1[12 + m];
    }
    lsum += (a0 + a1) + (a2 + a3);

    // pack pairs: w[tb][m] covers t = tb*32 + 8*(m>>1) + 4*hi + 2*(m&1) + {0,1}
    unsigned w0[8], w1[8];
#pragma unroll
    for (int m = 0; m < 8; ++m) {
      w0[m] = cvtpk(p0[2 * m], p0[2 * m + 1]);
      w1[m] = cvtpk(p1[2 * m], p1[2 * m + 1]);
    }
    // permlane32_swap: r0={A.lo,B.lo} -> word jl, r1={A.hi,B.hi} -> word jl+2
    unsigned paw[4][4];
#pragma unroll
    for (int tcl = 0; tcl < 2; ++tcl)
#pragma unroll
      for (int jl = 0; jl < 2; ++jl) {
        unsigned A0 = w0[4 * tcl + jl], B0 = w0[4 * tcl + 2 + jl];
        asm("v_permlane32_swap_b32 %0, %1" : "+v"(A0), "+v"(B0));
        paw[tcl][jl] = A0; paw[tcl][2 + jl] = B0;
        unsigned A1 = w1[4 * tcl + jl], B1 = w1[4 * tcl + 2 + jl];
        asm("v_permlane32_swap_b32 %0, %1" : "+v"(A1), "+v"(B1));
        paw[2 + tcl][jl] = A1; paw[2 + tcl][2 + jl] = B1;
      }
    bf16x8 pa[4];
#pragma unroll
    for (int tc = 0; tc < 4; ++tc) {
      u32x4 tw = {paw[tc][0], paw[tc][1], paw[tc][2], paw[tc][3]};
      pa[tc] = __builtin_bit_cast(bf16x8, tw);
    }

    __syncthreads();  // V(t) staged & X consumed by all waves

    if (t + 1 < NT) stageK();  // K(t+1), overlaps PV

    // ---- PV: o[db] += P . V  (A=pa in regs, B=V^T tile from LDS) ----
    int vcb = ((la & 7) << 4);
#pragma unroll
    for (int tc = 0; tc < 4; ++tc) {
      int bc = (tc * 32 + hi * 16) ^ vcb;
      bf16x8 vf0 = *(const bf16x8*)(Y + (la)      * 64 + (bc >> 1));
      bf16x8 vf1 = *(const bf16x8*)(Y + (32 + la) * 64 + (bc >> 1));
      bf16x8 vf2 = *(const bf16x8*)(Y + (64 + la) * 64 + (bc >> 1));
      bf16x8 vf3 = *(const bf16x8*)(Y + (96 + la) * 64 + (bc >> 1));
      o0 = __builtin_amdgcn_mfma_f32_32x32x16_bf16(pa[tc], vf0, o0, 0, 0, 0);
      o1 = __builtin_amdgcn_mfma_f32_32x32x16_bf16(pa[tc], vf1, o1, 0, 0, 0);
      o2 = __builtin_amdgcn_mfma_f32_32x32x16_bf16(pa[tc], vf2, o2, 0, 0, 0);
      o3 = __builtin_amdgcn_mfma_f32_32x32x16_bf16(pa[tc], vf3, o3, 0, 0, 0);
    }
    __syncthreads();  // K(t+1) staged & Y consumed by all waves
  }

  // ---- in-block split-K combine (through LDS; pipelines are dead now) ----
  {  // full half-row sum: own hi-half + partner hi-half
    float A = lsum, B = lsum;
    asm("v_permlane32_swap_b32 %0, %1" : "+v"(A), "+v"(B));
    lsum = A + B;
  }
  if (hi == 0) Lsh[wid][la] = lsum;
  float* fb = (float*)(&Xb[0][0]);  // 32KB scratch: [qw][64 floats][lane]
  if (kw == 1) {
    float* dst = fb + qw * 4096 + lane;
#pragma unroll
    for (int r = 0; r < 16; ++r) {
      dst[(r)      * 64] = o0[r];
      dst[(16 + r) * 64] = o1[r];
      dst[(32 + r) * 64] = o2[r];
      dst[(48 + r) * 64] = o3[r];
    }
  }
  __syncthreads();
  if (kw == 0) {
    float ltot = lsum + Lsh[wid + 2][la];
    float rinv = 1.0f / ltot;
    if (hi == 0) Lsh[wid][la] = rinv;   // same-wave LDS broadcast
    const float* src = fb + qw * 4096 + lane;
#pragma unroll
    for (int r = 0; r < 16; ++r) {
      o0[r] += src[(r)      * 64];
      o1[r] += src[(16 + r) * 64];
      o2[r] += src[(32 + r) * 64];
      o3[r] += src[(48 + r) * 64];
    }
    float rv[16];
#pragma unroll
    for (int r = 0; r < 16; ++r)
      rv[r] = Lsh[wid][(r & 3) + 8 * (r >> 2) + 4 * hi];
#pragma unroll
    for (int r = 0; r < 16; ++r) {
      int qrow = qb + (r & 3) + 8 * (r >> 2) + 4 * hi;
      short* orow = O + (size_t)qrow * Dm + h * HDim + la;
      orow[0]  = f2bf(o0[r] * rv[r]);
      orow[32] = f2bf(o1[r] * rv[r]);
      orow[64] = f2bf(o2[r] * rv[r]);
      orow[96] = f2bf(o3[r] * rv[r]);
    }
  }
}

extern "C" void kernel_launch(void* const* d_in, const int* in_sizes, int n_in,
                              void* d_out, int out_size, void* d_ws, size_t ws_size,
                              hipStream_t stream) {
  const float* x     = (const float*)d_in[0];
  const float* freqs = (const float*)d_in[3];
  const float* Wqkv  = (const float*)d_in[4];
  const float* bqkv  = (const float*)d_in[5];
  const float* gq    = (const float*)d_in[6];
  const float* gk    = (const float*)d_in[7];
  const float* Wo    = (const float*)d_in[8];
  const float* bo    = (const float*)d_in[9];
  float* out = (float*)d_out;

  char* w = (char*)d_ws;
  // region0: Q,K (head-major) + spare slot — xb and WqT overlaid (dead after GEMM1)
  short* Qb  = (short*)w;
  short* Kb  = Qb + (size_t)Sq * Dm;
  short* xb  = Qb;                      // 2560*1536 bf16, fits in Qb slot
  short* WqT = Kb;                      // 4608*1536 bf16, fits in Kb + spare slots
  size_t off = (size_t)3 * Sq * Dm * 2;
  short* WoT  = (short*)(w + off); off += (size_t)Dm * Dm * 2;
  short* qkvb = (short*)(w + off); off += (size_t)Sq * N3c * 2;
  short* VTb  = (short*)(w + off); off += (size_t)Sq * Dm * 2;
  short* AOb  = (short*)(w + off); off += (size_t)Sq * Dm * 2;

  // 1. fused preamble: x convert + both weight transposes in ONE launch
  k_prep<<<NCONV + NW1 + NW2, 256, 0, stream>>>(x, xb, Wqkv, WqT, Wo, WoT);
  // 2. QKV GEMM -> bf16 (BK=64, nt-major XCD chunk = r10 verified optimum)
  k_gemm_bt<1, 128, 1, 2><<<(Sq / 128) * (N3c / 128), 256, 0, stream>>>(xb, WqT, bqkv, qkvb,
                                                                        Sq, N3c, Dm, Sq / 128);
  // 3. fused mid-stage: RMS+RoPE (Q,K) + V^T straight from qkvb
  k_mid<<<Sq + NVT, 256, 0, stream>>>(qkvb, freqs, gq, gk, Qb, Kb, VTb);
  // 4. flash attention: 480 blocks (40 q-blocks x 12 heads), in-block split-K
  k_attn<<<480, 256, 0, stream>>>(Qb, Kb, VTb, AOb);
  // 5. output projection -> f32, BM=64 BK=64 mt-major (480 blocks ~2/CU;
  //    BM=128's 240 blocks underfill 256 CUs — r5: 9us slower).
  k_gemm_bt<0, 64, 0, 2><<<(Sq / 64) * (Dm / 128), 256, 0, stream>>>(AOb, WoT, bo, out,
                                                                     Sq, Dm, Dm, Dm / 128);
}